// Round 18
// baseline (124.114 us; speedup 1.0000x reference)
//
#include <hip/hip_runtime.h>
#include <hip/hip_bf16.h>
#include <math.h>

#define BB 64
#define DD 256
#define TT 24
#define NR 289

typedef float f32x4  __attribute__((ext_vector_type(4)));
typedef float f32x16 __attribute__((ext_vector_type(16)));
typedef short bf16x8 __attribute__((ext_vector_type(8)));

// ws layout (bytes) — ALL operands fragment-major (lane-minor, 16B/lane):
#define ETF_OFF  0ul                     // eTf  [64][32 sidx][32 r] bf16x8     1,048,576
#define VTF_OFF  1048576ul               // vTf  [64][10 nt][32 sidx][32 r]    10,485,760
#define VB2_OFF  11534336ul              // vbf2 [64][8 dt][40 ks][32 r]       10,485,760
#define EE_OFF   22020096ul              // eE   [64][8 dt][2 g2][12 reg][32 r] f32 1,572,864
#define SMAT_OFF 23592960ul              // Smat [4096] f32

// ---- merged conversion kernel: blocks 0..511 convert v, blocks 512..575 convert e.
__global__ __launch_bounds__(256) void conv_kernel(const float* __restrict__ e,
                                                   const float* __restrict__ v,
                                                   __hip_bfloat16* __restrict__ eTf,
                                                   float* __restrict__ eE,
                                                   __hip_bfloat16* __restrict__ vTf,
                                                   __hip_bfloat16* __restrict__ vbf2) {
    __shared__ float ld[32][321];
    int tid = threadIdx.x;

    if (blockIdx.x >= 512) {
        // ---------------- e -> eTf fragments + eE f32 fragments ----------------
        int i = blockIdx.x - 512;
        const float* ei = e + (size_t)i * DD * TT;
        bf16x8* dst = (bf16x8*)eTf + (size_t)i * 1024;
        #pragma unroll
        for (int p = 0; p < 4; ++p) {
            int idx = tid + p * 256;
            int r = idx & 31, sidx = idx >> 5;
            int d0 = sidx * 8;
            __hip_bfloat16 tmp[8];
            #pragma unroll
            for (int q = 0; q < 8; ++q) {
                float f = (r < TT) ? ei[(d0 + q) * TT + r] : 0.f;
                tmp[q] = __float2bfloat16(f);
            }
            dst[idx] = *(bf16x8*)tmp;
        }
        float* dstE = eE + (size_t)i * 6144;
        #pragma unroll
        for (int p = 0; p < 24; ++p) {
            int idx = tid + p * 256;
            int r = idx & 31, rest = idx >> 5;
            int reg = rest % 12, gdt = rest / 12;
            int g2 = gdt & 1, dt = gdt >> 1;
            int t = (reg & 3) + 8 * (reg >> 2) + 4 * g2;
            dstE[idx] = ei[(dt * 32 + r) * TT + t];
        }
        return;
    }

    // ---------------- v -> vTf (GEMM1 B) + vbf2 (GEMM2 B) ----------------------
    int j = blockIdx.x >> 3;
    int dbase = (blockIdx.x & 7) * 32;
    const float* vj = v + (size_t)j * DD * NR;
    for (int r = 0; r < 32; ++r) {
        const float* row = vj + (size_t)(dbase + r) * NR;
        ld[r][tid] = row[tid];
        if (tid < 64) {
            int n = 256 + tid;
            ld[r][n] = (n < NR) ? row[n] : 0.f;
        }
    }
    __syncthreads();
    {
        bf16x8* dT = (bf16x8*)vTf + (size_t)j * 10240;
        #pragma unroll
        for (int p = 0; p < 5; ++p) {
            int idx = tid + p * 256;
            int r = idx & 31, rest = idx >> 5;
            int nt = rest % 10, sl = rest / 10;
            int sidx = (dbase >> 3) + sl;
            __hip_bfloat16 tmp[8];
            #pragma unroll
            for (int q = 0; q < 8; ++q)
                tmp[q] = __float2bfloat16(ld[sl * 8 + q][nt * 32 + r]);
            dT[(nt * 32 + sidx) * 32 + r] = *(bf16x8*)tmp;
        }
    }
    {
        bf16x8* dB = (bf16x8*)vbf2 + (size_t)j * 10240;
        int dt = dbase >> 5;
        #pragma unroll
        for (int p = 0; p < 5; ++p) {
            int idx = tid + p * 256;
            int r = idx & 31, ks = idx >> 5;    // 0..39
            __hip_bfloat16 tmp[8];
            #pragma unroll
            for (int q = 0; q < 8; ++q)
                tmp[q] = __float2bfloat16(ld[r][ks * 8 + q]);
            dB[(dt * 40 + ks) * 32 + r] = *(bf16x8*)tmp;
        }
    }
}

// ---- one block (256 thr) per (i-PAIR, j): handles (i0,i1)=(2p,2p+1) for one j.
// Round-11 body replicated over 2 alpha buffers; every B fragment (vTf/vbf2,
// the load bulk) is loaded ONCE and feeds 2 MFMAs (one per i) -> per-pair
// B-load issue+stall halved. LDS 2x20480=40960 B -> 4 blocks/CU. (256,4).
__global__ __launch_bounds__(256, 4) void pair_kernel(const __hip_bfloat16* __restrict__ eTf,
                                                      const __hip_bfloat16* __restrict__ vTf,
                                                      const __hip_bfloat16* __restrict__ vbf2,
                                                      const float* __restrict__ eE,
                                                      float* __restrict__ Smat) {
    __shared__ __align__(16) __hip_bfloat16 alpha[2][32 * 320];   // 40960 B

    const int tid = threadIdx.x;
    const int wave = tid >> 6, lane = tid & 63;
    const int r = lane & 31, g2 = lane >> 5;
    // XCD swizzle: bijective over 2048 = 8*256; each XCD serves 8 j's.
    const int bid = (blockIdx.x & 7) * 256 + (blockIdx.x >> 3);
    const int j = bid >> 5;
    const int i0 = (bid & 31) * 2, i1 = i0 + 1;

    // pad-lite zeroing for BOTH buffers: rows 24..31 + swizzled cols 304..319.
    #pragma unroll
    for (int b = 0; b < 2; ++b) {
        char* ab = (char*)alpha[b];
        uint32_t* rz = (uint32_t*)(ab + 24 * 640);
        #pragma unroll
        for (int q = 0; q < 5; ++q) rz[tid + q * 256] = 0u;
        int t = tid >> 3, n0 = 304 + 2 * (tid & 7);
        int boff = (t * 640 + 2 * n0) ^ ((t & 7) << 4);
        *(uint32_t*)(ab + boff) = 0u;
    }
    // no barrier: pad regions only read in GEMM2, several barriers away.

    // ========== GEMM1: shared B fragment feeds both i's ========================
    const bf16x8* eF0 = (const bf16x8*)eTf + (size_t)i0 * 1024;
    const bf16x8* eF1 = (const bf16x8*)eTf + (size_t)i1 * 1024;
    const bf16x8* vF  = (const bf16x8*)vTf + (size_t)j * 10240;
    char* ab0 = (char*)alpha[0];
    char* ab1 = (char*)alpha[1];
    #pragma unroll
    for (int ti = 0; ti < 3; ++ti) {
        int nt2 = wave + ti * 4;               // 10 n-tiles over 4 waves
        if (nt2 < 10) {                        // wave-uniform
            f32x16 a0, a1;
            #pragma unroll
            for (int z = 0; z < 16; ++z) { a0[z] = 0.f; a1[z] = 0.f; }
            int n = nt2 * 32 + r;
            #pragma unroll
            for (int s = 0; s < 16; ++s) {
                bf16x8 bf = vF[(nt2 * 32 + s * 2 + g2) * 32 + r];
                a0 = __builtin_amdgcn_mfma_f32_32x32x16_bf16(eF0[(s * 2 + g2) * 32 + r], bf, a0, 0, 0, 0);
                a1 = __builtin_amdgcn_mfma_f32_32x32x16_bf16(eF1[(s * 2 + g2) * 32 + r], bf, a1, 0, 0, 0);
            }
            if (nt2 < 9 || r < 16) {
                #pragma unroll
                for (int reg = 0; reg < 12; ++reg) {
                    int t = (reg & 3) + 8 * (reg >> 2) + 4 * g2;   // < 24
                    int boff = (t * 640 + 2 * n) ^ ((t & 7) << 4);
                    *(__hip_bfloat16*)(ab0 + boff) = __float2bfloat16(a0[reg]);
                    *(__hip_bfloat16*)(ab1 + boff) = __float2bfloat16(a1[reg]);
                }
            }
        }
    }
    __syncthreads();

    // ============ softmax over n, per buffer (wave owns 6 t-rows) ==============
    #pragma unroll
    for (int b = 0; b < 2; ++b) {
        char* ab = (char*)alpha[b];
        #pragma unroll
        for (int tt = 0; tt < 6; ++tt) {
            int t = wave * 6 + tt;
            int base = t * 640, sw = (t & 7) << 4;
            float vls[5];
            #pragma unroll
            for (int k5 = 0; k5 < 5; ++k5) {
                int n = k5 * 64 + lane;
                vls[k5] = (n < NR)
                    ? __bfloat162float(*(const __hip_bfloat16*)(ab + ((base + 2 * n) ^ sw)))
                    : -INFINITY;
            }
            float m = vls[0];
            #pragma unroll
            for (int k5 = 1; k5 < 5; ++k5) m = fmaxf(m, vls[k5]);
            #pragma unroll
            for (int mk = 32; mk >= 1; mk >>= 1) m = fmaxf(m, __shfl_xor(m, mk, 64));
            float sum = 0.f;
            #pragma unroll
            for (int k5 = 0; k5 < 5; ++k5) { vls[k5] = __expf(vls[k5] - m); sum += vls[k5]; }
            #pragma unroll
            for (int mk = 32; mk >= 1; mk >>= 1) sum += __shfl_xor(sum, mk, 64);
            float inv = 1.f / sum;
            #pragma unroll
            for (int k5 = 0; k5 < 5; ++k5) {
                int n = k5 * 64 + lane;
                if (n < NR)
                    *(__hip_bfloat16*)(ab + ((base + 2 * n) ^ sw)) = __float2bfloat16(vls[k5] * inv);
            }
        }
    }
    __syncthreads();

    // ====== softmax over t, per buffer, per column (thread <-> n) ==============
    #pragma unroll
    for (int b = 0; b < 2; ++b) {
        char* ab = (char*)alpha[b];
        for (int p = 0; p < 2; ++p) {
            int n = p * 256 + tid;
            if (n < NR) {
                float vals[TT];
                #pragma unroll
                for (int t = 0; t < TT; ++t)
                    vals[t] = __bfloat162float(
                        *(const __hip_bfloat16*)(ab + ((t * 640 + 2 * n) ^ ((t & 7) << 4))));
                float m = vals[0];
                #pragma unroll
                for (int t = 1; t < TT; ++t) m = fmaxf(m, vals[t]);
                m *= 4.0f;
                float sum = 0.f;
                #pragma unroll
                for (int t = 0; t < TT; ++t) { vals[t] = __expf(4.0f * vals[t] - m); sum += vals[t]; }
                float inv = 1.f / sum;
                #pragma unroll
                for (int t = 0; t < TT; ++t)
                    *(__hip_bfloat16*)(ab + ((t * 640 + 2 * n) ^ ((t & 7) << 4))) =
                        __float2bfloat16(vals[t] * inv);
            }
        }
    }
    __syncthreads();

    // ====== GEMM2: shared B fragment feeds both i's; fused epilogue ============
    const bf16x8* vB2f = (const bf16x8*)vbf2 + (size_t)j * 10240;
    const float* eE0 = eE + (size_t)i0 * 6144;
    const float* eE1 = eE + (size_t)i1 * 6144;

    float ss0 = 0.f, ss1 = 0.f;
    #pragma unroll
    for (int ti2 = 0; ti2 < 2; ++ti2) {
        int dt = wave + ti2 * 4;               // 8 d-tiles over 4 waves
        f32x16 a0, a1;
        #pragma unroll
        for (int z = 0; z < 16; ++z) { a0[z] = 0.f; a1[z] = 0.f; }
        int sw = (r & 7) << 4;
        #pragma unroll
        for (int ks = 0; ks < 20; ++ks) {
            bf16x8 bf = vB2f[(dt * 40 + ks * 2 + g2) * 32 + r];
            int boff = (r * 640 + ks * 32 + g2 * 16) ^ sw;
            bf16x8 af0 = *(const bf16x8*)(ab0 + boff);
            bf16x8 af1 = *(const bf16x8*)(ab1 + boff);
            a0 = __builtin_amdgcn_mfma_f32_32x32x16_bf16(af0, bf, a0, 0, 0, 0);
            a1 = __builtin_amdgcn_mfma_f32_32x32x16_bf16(af1, bf, a1, 0, 0, 0);
        }
        // epilogue: cosine over t for this lane's d column, both i's
        float d0 = 0.f, c0 = 0.f, e0 = 0.f, d1 = 0.f, c1 = 0.f, e1 = 0.f;
        #pragma unroll
        for (int reg = 0; reg < 12; ++reg) {
            int off = ((dt * 2 + g2) * 12 + reg) * 32 + r;
            float ev0 = eE0[off], ev1 = eE1[off];
            d0 = fmaf(a0[reg], ev0, d0); c0 = fmaf(a0[reg], a0[reg], c0); e0 = fmaf(ev0, ev0, e0);
            d1 = fmaf(a1[reg], ev1, d1); c1 = fmaf(a1[reg], a1[reg], c1); e1 = fmaf(ev1, ev1, e1);
        }
        d0 += __shfl_xor(d0, 32, 64); c0 += __shfl_xor(c0, 32, 64); e0 += __shfl_xor(e0, 32, 64);
        d1 += __shfl_xor(d1, 32, 64); c1 += __shfl_xor(c1, 32, 64); e1 += __shfl_xor(e1, 32, 64);
        float R0 = d0 / fmaxf(sqrtf(c0) * sqrtf(e0), 1e-8f);
        float R1 = d1 / fmaxf(sqrtf(c1) * sqrtf(e1), 1e-8f);
        ss0 += __expf(5.f * R0);               // 5R in [-5,5]: plain sum is safe
        ss1 += __expf(5.f * R1);
    }
    // butterfly-sum over the wave (each d counted twice: lanes l and l^32)
    #pragma unroll
    for (int mk = 1; mk <= 32; mk <<= 1) { ss0 += __shfl_xor(ss0, mk, 64); ss1 += __shfl_xor(ss1, mk, 64); }
    __syncthreads();                           // all waves done reading alpha
    float* red = (float*)alpha[0];             // [8]: 2 x 4 waves
    if (lane == 0) { red[wave] = ss0; red[4 + wave] = ss1; }
    __syncthreads();
    if (tid == 0) {
        float t0 = red[0] + red[1] + red[2] + red[3];
        float t1 = red[4] + red[5] + red[6] + red[7];
        Smat[j * 64 + i0] = powf(logf(t0 * 0.5f), 0.2f);   // /2: lane-pair duplication
        Smat[j * 64 + i1] = powf(logf(t1 * 0.5f), 0.2f);
    }
}

// out[0..63] = sum_j S[i][j]; out[64..127] = sum_i S[i][j]
__global__ void reduce_kernel(const float* __restrict__ Smat, float* __restrict__ out) {
    int k = threadIdx.x;   // 0..127
    float s = 0.f;
    if (k < 64) {
        int i = k;
        for (int j = 0; j < BB; ++j) s += Smat[j * 64 + i];
        out[i] = s;
    } else {
        int jq = k - 64;
        for (int i = 0; i < BB; ++i) s += Smat[jq * 64 + i];
        out[64 + jq] = s;
    }
}

extern "C" void kernel_launch(void* const* d_in, const int* in_sizes, int n_in,
                              void* d_out, int out_size, void* d_ws, size_t ws_size,
                              hipStream_t stream) {
    const float* e = (const float*)d_in[0];
    const float* v = (const float*)d_in[1];
    float* out = (float*)d_out;
    char* ws = (char*)d_ws;
    __hip_bfloat16* eTf  = (__hip_bfloat16*)(ws + ETF_OFF);
    __hip_bfloat16* vTf  = (__hip_bfloat16*)(ws + VTF_OFF);
    __hip_bfloat16* vbf2 = (__hip_bfloat16*)(ws + VB2_OFF);
    float* eE  = (float*)(ws + EE_OFF);
    float* Smat = (float*)(ws + SMAT_OFF);

    conv_kernel<<<576, 256, 0, stream>>>(e, v, eTf, eE, vTf, vbf2);
    pair_kernel<<<2048, 256, 0, stream>>>(eTf, vTf, vbf2, eE, Smat);
    reduce_kernel<<<1, 128, 0, stream>>>(Smat, out);
}

// Round 19
// 104.257 us; speedup vs baseline: 1.1905x; 1.1905x over previous
//
#include <hip/hip_runtime.h>
#include <hip/hip_bf16.h>
#include <math.h>

#define BB 64
#define DD 256
#define TT 24
#define NR 289

typedef float f32x4  __attribute__((ext_vector_type(4)));
typedef float f32x16 __attribute__((ext_vector_type(16)));
typedef short bf16x8 __attribute__((ext_vector_type(8)));

// ws layout (bytes) — ALL operands fragment-major (lane-minor, 16B/lane):
#define ETF_OFF  0ul                     // eTf  [64][32 sidx][32 r] bf16x8     1,048,576
#define VTF_OFF  1048576ul               // vTf  [64][10 nt][32 sidx][32 r]    10,485,760
#define VB2_OFF  11534336ul              // vbf2 [64][8 dt][40 ks][32 r]       10,485,760
#define EE_OFF   22020096ul              // eE   [64][8 dt][2 g2][12 reg][32 r] f32 1,572,864
#define SMAT_OFF 23592960ul              // Smat [4096] f32

// ---- merged conversion kernel: blocks 0..511 convert v, blocks 512..575 convert e.
__global__ __launch_bounds__(256) void conv_kernel(const float* __restrict__ e,
                                                   const float* __restrict__ v,
                                                   __hip_bfloat16* __restrict__ eTf,
                                                   float* __restrict__ eE,
                                                   __hip_bfloat16* __restrict__ vTf,
                                                   __hip_bfloat16* __restrict__ vbf2) {
    __shared__ float ld[32][321];
    int tid = threadIdx.x;

    if (blockIdx.x >= 512) {
        // ---------------- e -> eTf fragments + eE f32 fragments ----------------
        int i = blockIdx.x - 512;
        const float* ei = e + (size_t)i * DD * TT;
        bf16x8* dst = (bf16x8*)eTf + (size_t)i * 1024;
        #pragma unroll
        for (int p = 0; p < 4; ++p) {
            int idx = tid + p * 256;
            int r = idx & 31, sidx = idx >> 5;
            int d0 = sidx * 8;
            __hip_bfloat16 tmp[8];
            #pragma unroll
            for (int q = 0; q < 8; ++q) {
                float f = (r < TT) ? ei[(d0 + q) * TT + r] : 0.f;
                tmp[q] = __float2bfloat16(f);
            }
            dst[idx] = *(bf16x8*)tmp;
        }
        float* dstE = eE + (size_t)i * 6144;
        #pragma unroll
        for (int p = 0; p < 24; ++p) {
            int idx = tid + p * 256;
            int r = idx & 31, rest = idx >> 5;
            int reg = rest % 12, gdt = rest / 12;
            int g2 = gdt & 1, dt = gdt >> 1;
            int t = (reg & 3) + 8 * (reg >> 2) + 4 * g2;
            dstE[idx] = ei[(dt * 32 + r) * TT + t];
        }
        return;
    }

    // ---------------- v -> vTf (GEMM1 B) + vbf2 (GEMM2 B) ----------------------
    int j = blockIdx.x >> 3;
    int dbase = (blockIdx.x & 7) * 32;
    const float* vj = v + (size_t)j * DD * NR;
    for (int r = 0; r < 32; ++r) {
        const float* row = vj + (size_t)(dbase + r) * NR;
        ld[r][tid] = row[tid];
        if (tid < 64) {
            int n = 256 + tid;
            ld[r][n] = (n < NR) ? row[n] : 0.f;
        }
    }
    __syncthreads();
    {
        bf16x8* dT = (bf16x8*)vTf + (size_t)j * 10240;
        #pragma unroll
        for (int p = 0; p < 5; ++p) {
            int idx = tid + p * 256;
            int r = idx & 31, rest = idx >> 5;
            int nt = rest % 10, sl = rest / 10;
            int sidx = (dbase >> 3) + sl;
            __hip_bfloat16 tmp[8];
            #pragma unroll
            for (int q = 0; q < 8; ++q)
                tmp[q] = __float2bfloat16(ld[sl * 8 + q][nt * 32 + r]);
            dT[(nt * 32 + sidx) * 32 + r] = *(bf16x8*)tmp;
        }
    }
    {
        bf16x8* dB = (bf16x8*)vbf2 + (size_t)j * 10240;
        int dt = dbase >> 5;
        #pragma unroll
        for (int p = 0; p < 5; ++p) {
            int idx = tid + p * 256;
            int r = idx & 31, ks = idx >> 5;    // 0..39
            __hip_bfloat16 tmp[8];
            #pragma unroll
            for (int q = 0; q < 8; ++q)
                tmp[q] = __float2bfloat16(ld[r][ks * 8 + q]);
            dB[(dt * 40 + ks) * 32 + r] = *(bf16x8*)tmp;
        }
    }
}

// ---- one block (256 thr) per (i,j) pair; Smat[j*64+i] = S[i][j]
// BYTE-EXACT round-11 champion body (90.4 us pair): coalesced fragment-major
// operands, LDS bf16 softmaxes, (256,6), XCD swizzle, pad-lite zeroing.
// Rounds 12-18 established every mutation of this body regresses; do not touch.
__global__ __launch_bounds__(256, 6) void pair_kernel(const __hip_bfloat16* __restrict__ eTf,
                                                      const __hip_bfloat16* __restrict__ vTf,
                                                      const __hip_bfloat16* __restrict__ vbf2,
                                                      const float* __restrict__ eE,
                                                      float* __restrict__ Smat) {
    __shared__ __align__(16) __hip_bfloat16 alpha[32 * 320];   // 20480 B, XOR-swizzled rows

    const int tid = threadIdx.x;
    const int wave = tid >> 6, lane = tid & 63;
    const int r = lane & 31, g2 = lane >> 5;
    // XCD swizzle (T1): bijective (4096 = 8*512)
    const int bid = (blockIdx.x & 7) * 512 + (blockIdx.x >> 3);
    const int i = bid & 63, j = bid >> 6;

    char* ab = (char*)alpha;

    // pad-lite zeroing: rows 24..31 and swizzled cols 304..319 of all rows.
    {
        uint32_t* rz = (uint32_t*)(ab + 24 * 640);   // 8 rows * 640 B
        #pragma unroll
        for (int q = 0; q < 5; ++q) rz[tid + q * 256] = 0u;
        int t = tid >> 3, n0 = 304 + 2 * (tid & 7);
        int boff = (t * 640 + 2 * n0) ^ ((t & 7) << 4);
        *(uint32_t*)(ab + boff) = 0u;
    }
    // no barrier: pad region only read in GEMM2, three barriers away.

    // ========== GEMM1: s[t][n] = sum_d e^T v, 32x32 tiles, coalesced frags =====
    const bf16x8* eF = (const bf16x8*)eTf + (size_t)i * 1024;
    const bf16x8* vF = (const bf16x8*)vTf + (size_t)j * 10240;
    #pragma unroll
    for (int ti = 0; ti < 3; ++ti) {
        int nt2 = wave + ti * 4;               // 10 n-tiles over 4 waves
        if (nt2 < 10) {                        // wave-uniform
            f32x16 acc;
            #pragma unroll
            for (int z = 0; z < 16; ++z) acc[z] = 0.f;
            int n = nt2 * 32 + r;
            #pragma unroll
            for (int s = 0; s < 16; ++s) {
                bf16x8 af = eF[(s * 2 + g2) * 32 + r];
                bf16x8 bf = vF[(nt2 * 32 + s * 2 + g2) * 32 + r];
                acc = __builtin_amdgcn_mfma_f32_32x32x16_bf16(af, bf, acc, 0, 0, 0);
            }
            // write scores t<24 (regs 0..11); tile 9 lanes r>=16 (n>=304) skip
            if (nt2 < 9 || r < 16) {
                #pragma unroll
                for (int reg = 0; reg < 12; ++reg) {
                    int t = (reg & 3) + 8 * (reg >> 2) + 4 * g2;   // < 24
                    int boff = (t * 640 + 2 * n) ^ ((t & 7) << 4);
                    *(__hip_bfloat16*)(ab + boff) = __float2bfloat16(acc[reg]);
                }
            }
        }
    }
    __syncthreads();

    // ============ softmax over n, in place on bf16 rows (wave owns 6 t-rows) ====
    #pragma unroll
    for (int tt = 0; tt < 6; ++tt) {
        int t = wave * 6 + tt;
        int base = t * 640, sw = (t & 7) << 4;
        float vls[5];
        #pragma unroll
        for (int k5 = 0; k5 < 5; ++k5) {
            int n = k5 * 64 + lane;
            vls[k5] = (n < NR)
                ? __bfloat162float(*(const __hip_bfloat16*)(ab + ((base + 2 * n) ^ sw)))
                : -INFINITY;
        }
        float m = vls[0];
        #pragma unroll
        for (int k5 = 1; k5 < 5; ++k5) m = fmaxf(m, vls[k5]);
        #pragma unroll
        for (int mk = 32; mk >= 1; mk >>= 1) m = fmaxf(m, __shfl_xor(m, mk, 64));
        float sum = 0.f;
        #pragma unroll
        for (int k5 = 0; k5 < 5; ++k5) { vls[k5] = __expf(vls[k5] - m); sum += vls[k5]; }
        #pragma unroll
        for (int mk = 32; mk >= 1; mk >>= 1) sum += __shfl_xor(sum, mk, 64);
        float inv = 1.f / sum;
        #pragma unroll
        for (int k5 = 0; k5 < 5; ++k5) {
            int n = k5 * 64 + lane;
            if (n < NR)
                *(__hip_bfloat16*)(ab + ((base + 2 * n) ^ sw)) = __float2bfloat16(vls[k5] * inv);
        }
    }
    __syncthreads();

    // ====== softmax over t of G1*s_norm, in place per column (thread <-> n) =====
    for (int p = 0; p < 2; ++p) {
        int n = p * 256 + tid;
        if (n < NR) {
            float vals[TT];
            #pragma unroll
            for (int t = 0; t < TT; ++t)
                vals[t] = __bfloat162float(
                    *(const __hip_bfloat16*)(ab + ((t * 640 + 2 * n) ^ ((t & 7) << 4))));
            float m = vals[0];
            #pragma unroll
            for (int t = 1; t < TT; ++t) m = fmaxf(m, vals[t]);
            m *= 4.0f;
            float sum = 0.f;
            #pragma unroll
            for (int t = 0; t < TT; ++t) { vals[t] = __expf(4.0f * vals[t] - m); sum += vals[t]; }
            float inv = 1.f / sum;
            #pragma unroll
            for (int t = 0; t < TT; ++t)
                *(__hip_bfloat16*)(ab + ((t * 640 + 2 * n) ^ ((t & 7) << 4))) =
                    __float2bfloat16(vals[t] * inv);
        }
    }
    __syncthreads();

    // ====== GEMM2: c[t][d] = sum_n alpha[t][n]*v[d][n], 32x32 tiles =============
    const bf16x8* vB2f = (const bf16x8*)vbf2 + (size_t)j * 10240;
    const float* eEp = eE + (size_t)i * 6144;

    float ssum = 0.f;
    #pragma unroll
    for (int ti2 = 0; ti2 < 2; ++ti2) {
        int dt = wave + ti2 * 4;               // 8 d-tiles over 4 waves
        f32x16 acc;
        #pragma unroll
        for (int z = 0; z < 16; ++z) acc[z] = 0.f;
        int sw = (r & 7) << 4;
        #pragma unroll
        for (int ks = 0; ks < 20; ++ks) {
            bf16x8 af = *(const bf16x8*)(ab + ((r * 640 + ks * 32 + g2 * 16) ^ sw));
            bf16x8 bf = vB2f[(dt * 40 + ks * 2 + g2) * 32 + r];
            acc = __builtin_amdgcn_mfma_f32_32x32x16_bf16(af, bf, acc, 0, 0, 0);
        }
        // epilogue: cosine over t for this lane's d column (12 t's here, 12 in l^32)
        float dot = 0.f, cn2 = 0.f, en2 = 0.f;
        #pragma unroll
        for (int reg = 0; reg < 12; ++reg) {
            float ev = eEp[((dt * 2 + g2) * 12 + reg) * 32 + r];
            dot = fmaf(acc[reg], ev, dot);
            cn2 = fmaf(acc[reg], acc[reg], cn2);
            en2 = fmaf(ev, ev, en2);
        }
        dot += __shfl_xor(dot, 32, 64);
        cn2 += __shfl_xor(cn2, 32, 64);
        en2 += __shfl_xor(en2, 32, 64);
        float R = dot / fmaxf(sqrtf(cn2) * sqrtf(en2), 1e-8f);
        ssum += __expf(5.f * R);               // 5R in [-5,5]: plain sum is safe
    }
    // butterfly-sum over the wave (each d counted twice: lanes l and l^32)
    #pragma unroll
    for (int mk = 1; mk <= 32; mk <<= 1) ssum += __shfl_xor(ssum, mk, 64);
    __syncthreads();                           // all waves done reading alpha
    float* red = (float*)alpha;
    if (lane == 0) red[wave] = ssum;
    __syncthreads();
    if (tid == 0) {
        float total = red[0] + red[1] + red[2] + red[3];
        float lse = logf(total * 0.5f);        // /2 removes the lane-pair duplication
        Smat[bid] = powf(lse, 0.2f);
    }
}

// out[0..63] = sum_j S[i][j]; out[64..127] = sum_i S[i][j]
__global__ void reduce_kernel(const float* __restrict__ Smat, float* __restrict__ out) {
    int k = threadIdx.x;   // 0..127
    float s = 0.f;
    if (k < 64) {
        int i = k;
        for (int j = 0; j < BB; ++j) s += Smat[j * 64 + i];
        out[i] = s;
    } else {
        int jq = k - 64;
        for (int i = 0; i < BB; ++i) s += Smat[jq * 64 + i];
        out[64 + jq] = s;
    }
}

extern "C" void kernel_launch(void* const* d_in, const int* in_sizes, int n_in,
                              void* d_out, int out_size, void* d_ws, size_t ws_size,
                              hipStream_t stream) {
    const float* e = (const float*)d_in[0];
    const float* v = (const float*)d_in[1];
    float* out = (float*)d_out;
    char* ws = (char*)d_ws;
    __hip_bfloat16* eTf  = (__hip_bfloat16*)(ws + ETF_OFF);
    __hip_bfloat16* vTf  = (__hip_bfloat16*)(ws + VTF_OFF);
    __hip_bfloat16* vbf2 = (__hip_bfloat16*)(ws + VB2_OFF);
    float* eE  = (float*)(ws + EE_OFF);
    float* Smat = (float*)(ws + SMAT_OFF);

    conv_kernel<<<576, 256, 0, stream>>>(e, v, eTf, eE, vTf, vbf2);
    pair_kernel<<<BB * BB, 256, 0, stream>>>(eTf, vTf, vbf2, eE, Smat);
    reduce_kernel<<<1, 128, 0, stream>>>(Smat, out);
}